// Round 11
// baseline (400.371 us; speedup 1.0000x reference)
//
#include <hip/hip_runtime.h>

#define NN 50000
#define EE 800000
#define DD 128
#define RR 8
#define KSTACK 1152    // (RR+1)*DD stacked K
#define NR2 (NN * RR)  // 400000
#define RPB 16         // dst rows per fused block
#define ROWB 2304      // bytes per A-tile row (1152 bf16; XOR swizzle, no pad)

typedef __attribute__((ext_vector_type(8))) short bf16x8;
typedef __attribute__((ext_vector_type(4))) float f32x4;

__device__ inline float bf2f(ushort u) {
    union { uint i; float f; } v; v.i = ((uint)u) << 16; return v.f;
}
__device__ inline ushort f2bf(float f) {
    uint b = __float_as_uint(f);
    uint r = (b + 0x7fffu + ((b >> 16) & 1u)) >> 16;
    return (ushort)r;
}

// Tiled weight build with LDS transpose: coalesced basis reads (o-major),
// coalesced 32B wT writes (k-major). Grid: (36 k-tiles, 2 layers).
__global__ void __launch_bounds__(256) k_build_w3(
        const float* __restrict__ b0, const float* __restrict__ c0,
        const float* __restrict__ r0, const float* __restrict__ b1,
        const float* __restrict__ c1, const float* __restrict__ r1,
        ushort* __restrict__ w0, ushort* __restrict__ w1) {
    __shared__ float tile[32][132];
    const float* basis = blockIdx.y ? b1 : b0;
    const float* comp  = blockIdx.y ? c1 : c0;
    const float* root  = blockIdx.y ? r1 : r0;
    ushort* wT         = blockIdx.y ? w1 : w0;
    int tid = threadIdx.x;
    int k0 = blockIdx.x * 32;
    #pragma unroll
    for (int it = 0; it < 16; ++it) {
        int idx = it * 256 + tid;
        int kk = idx >> 7, o = idx & 127;
        int k = k0 + kk;
        float val;
        if (k < RR * DD) {
            int r = k >> 7, i = k & 127;
            float s = 0.f;
            #pragma unroll
            for (int b = 0; b < 8; ++b) s += comp[r * 8 + b] * basis[(b * 128 + i) * 128 + o];
            val = s;
        } else {
            val = root[(k - RR * DD) * 128 + o];
        }
        tile[kk][o] = val;
    }
    __syncthreads();
    int o = tid >> 1, half = tid & 1;
    ushort* wp = wT + (size_t)o * KSTACK + k0 + half * 16;
    #pragma unroll
    for (int j = 0; j < 8; ++j) {
        float lo = tile[half * 16 + 2 * j][o];
        float hi = tile[half * 16 + 2 * j + 1][o];
        uint pk;
        asm("v_cvt_pk_bf16_f32 %0, %1, %2" : "=v"(pk) : "v"(lo), "v"(hi));
        *(uint*)(wp + 2 * j) = pk;
    }
}

__global__ void k_cvt_bf16(const float* __restrict__ x, ushort* __restrict__ xb, int n4) {
    int i = blockIdx.x * 256 + threadIdx.x;
    if (i < n4) {
        float4 v = ((const float4*)x)[i];
        uint2 p;
        p.x = (uint)f2bf(v.x) | ((uint)f2bf(v.y) << 16);
        p.y = (uint)f2bf(v.z) | ((uint)f2bf(v.w) << 16);
        ((uint2*)xb)[i] = p;
    }
}

__global__ void k_hist(const int* __restrict__ ei, const int* __restrict__ et,
                       int* __restrict__ deg_dr) {
    int e = blockIdx.x * 256 + threadIdx.x;
    if (e < EE) atomicAdd(&deg_dr[ei[EE + e] * RR + et[e]], 1);
}

__device__ inline int rowdeg(const int* __restrict__ deg_dr, int n) {
    int4 a = ((const int4*)deg_dr)[2 * n];
    int4 b = ((const int4*)deg_dr)[2 * n + 1];
    return a.x + a.y + a.z + a.w + b.x + b.y + b.z + b.w;
}

__global__ void k_scan1(const int* __restrict__ deg_dr, int* __restrict__ bsum, int n) {
    __shared__ int s[256];
    int t = threadIdx.x;
    int i = blockIdx.x * 256 + t;
    s[t] = (i < n) ? rowdeg(deg_dr, i) : 0;
    __syncthreads();
    for (int o = 128; o > 0; o >>= 1) {
        if (t < o) s[t] += s[t + o];
        __syncthreads();
    }
    if (t == 0) bsum[blockIdx.x] = s[0];
}

__global__ void k_scan2(int* __restrict__ bsum, int nb) {
    __shared__ int s[256];
    int t = threadIdx.x;
    int v = (t < nb) ? bsum[t] : 0;
    s[t] = v;
    __syncthreads();
    for (int o = 1; o < 256; o <<= 1) {
        int u = (t >= o) ? s[t - o] : 0;
        __syncthreads();
        s[t] += u;
        __syncthreads();
    }
    if (t < nb) bsum[t] = s[t] - v;   // exclusive
}

__global__ void k_scan3(const int* __restrict__ deg_dr, const int* __restrict__ boff,
                        int* __restrict__ ptr, int n) {
    __shared__ int s[256];
    int t = threadIdx.x;
    int i = blockIdx.x * 256 + t;
    int v = (i < n) ? rowdeg(deg_dr, i) : 0;
    s[t] = v;
    __syncthreads();
    for (int o = 1; o < 256; o <<= 1) {
        int u = (t >= o) ? s[t - o] : 0;
        __syncthreads();
        s[t] += u;
        __syncthreads();
    }
    if (i < n) ptr[i + 1] = boff[blockIdx.x] + s[t];
    if (i == 0) ptr[0] = 0;
}

// Per edge at (dst,rel)-sorted position:
//   ekw.x = (base16<<19) | ((lrow&7)<<16) | src,  base16 = (lrow*ROWB + rel*256)>>4
//   ekw.y = 1/deg(dst,rel)
__global__ void k_scatter(const int* __restrict__ ei, const int* __restrict__ et,
                          const int* __restrict__ row_ptr, const int* __restrict__ deg_dr,
                          int* __restrict__ cursor, int2* __restrict__ ekw) {
    int e = blockIdx.x * 256 + threadIdx.x;
    if (e < EE) {
        int s = ei[e], d = ei[EE + e], t = et[e];
        int4 a = ((const int4*)deg_dr)[2 * d];
        int4 b = ((const int4*)deg_dr)[2 * d + 1];
        int pre = 0;
        pre += (t > 0) ? a.x : 0; pre += (t > 1) ? a.y : 0;
        pre += (t > 2) ? a.z : 0; pre += (t > 3) ? a.w : 0;
        pre += (t > 4) ? b.x : 0; pre += (t > 5) ? b.y : 0;
        pre += (t > 6) ? b.z : 0;
        int deg = (t == 0) ? a.x : (t == 1) ? a.y : (t == 2) ? a.z : (t == 3) ? a.w
                : (t == 4) ? b.x : (t == 5) ? b.y : (t == 6) ? b.z : b.w;
        int p = row_ptr[d] + pre + atomicAdd(&cursor[d * RR + t], 1);
        int lrow = d & (RPB - 1);
        int base16 = lrow * (ROWB >> 4) + t * 16;
        int2 pk;
        pk.x = (base16 << 19) | ((lrow & 7) << 16) | s;
        pk.y = __float_as_int(1.f / (float)deg);
        ekw[p] = pk;
    }
}

// Fused layer. Block = 16 dst rows, 512 threads (8 waves), 37.1KB LDS.
// launch_bounds(512,8): VGPR cap 64 -> 4 blocks/CU = 32 waves/CU.
// Phase 1: wave owns 2 rows as one flat (dst,rel)-sorted edge stream, written
//   as the SIMPLEST possible loop so the compiler software-pipelines it:
//   uniform p (SGPR) -> ekw[p] is a scalar SMEM load (off the VMEM path);
//   gather = SGPR row base + lane offset; run-accumulate in registers,
//   unconditional overwrite-flush to the bf16 A-tile (last write of each
//   (row,rel)-run holds the full f32 sum). Wave-local zero of own rows
//   (no pre-gather barrier). No manual pipeline, no dummies, no readlane.
// Phase 2: 36 K-step MFMA GEMM [16x1152]@[1152x128]; wave -> 16 cols (1 frag);
//   A from XOR-swizzled LDS, B streamed from L2-resident wT; bias (+ReLU).
__global__ void __launch_bounds__(512, 8) k_fused9(
        const ushort* __restrict__ in, const int* __restrict__ rp,
        const int2* __restrict__ ekw, const ushort* __restrict__ BT,
        const float* __restrict__ bias, ushort* __restrict__ hout,
        float* __restrict__ fout) {
    __shared__ uint4 at4[RPB * ROWB / 16];   // 36,864 B
    char* atb = (char*)at4;
    int tid = threadIdx.x, wid = tid >> 6, lane = tid & 63;
    int blockrow = blockIdx.x * RPB;
    uint lane4 = (uint)lane << 2;

    // wave-local zero of own 2 rows (each wave touches only its rows until the barrier)
    {
        uint4 z = {0u, 0u, 0u, 0u};
        #pragma unroll
        for (int r = 0; r < 2; ++r) {
            char* zb = atb + (wid * 2 + r) * ROWB + lane * 16;
            *(uint4*)(zb) = z;
            *(uint4*)(zb + 1024) = z;
            if (lane < 16) *(uint4*)(zb + 2048) = z;
        }
    }

    const ushort* inl = in + (lane << 1);

    // self (root) slots, coalesced reads (grid exact: all rows valid)
    #pragma unroll
    for (int rr = 0; rr < 2; ++rr) {
        int lr = (wid << 1) + rr;
        int n = blockrow + lr;
        uint su = *(const uint*)(inl + (size_t)n * DD);
        uint off = (uint)(lr * ROWB + 2048) + (lane4 ^ ((uint)(lr & 7) << 4));
        *(uint*)(atb + off) = su;
    }

    // flat edge range for this wave's 2 rows — simple loop, compiler-scheduled
    int n0 = blockrow + (wid << 1);
    int p    = __builtin_amdgcn_readfirstlane(rp[n0]);
    int pend = __builtin_amdgcn_readfirstlane(rp[n0 + 2]);

    float a0 = 0.f, a1 = 0.f;
    uint prev = 0xFFFFFFFFu;
    #pragma unroll 4
    for (; p < pend; ++p) {
        int2 e = ekw[p];                 // uniform address -> scalar load
        uint ex = (uint)e.x;
        uint g = *(const uint*)(inl + (size_t)(ex & 0xFFFFu) * DD);
        float w = __int_as_float(e.y);
        uint off = ((ex >> 19) << 4) + (lane4 ^ ((ex >> 12) & 0x70u));
        bool same = (off == prev);
        a0 = same ? a0 : 0.f;
        a1 = same ? a1 : 0.f;
        a0 += w * bf2f((ushort)(g & 0xFFFFu));
        a1 += w * bf2f((ushort)(g >> 16));
        uint pk;
        asm("v_cvt_pk_bf16_f32 %0, %1, %2" : "=v"(pk) : "v"(a0), "v"(a1));
        *(uint*)(atb + off) = pk;
        prev = off;
    }
    __syncthreads();

    // Phase 2: wave wid -> cols [wid*16, wid*16+16), rows 0..15 (1 fragment).
    int rlo = lane & 15, q = lane >> 4;
    int colbase = wid << 4;
    uint x7 = (uint)(rlo & 7) << 4;
    const char* arow = atb + rlo * ROWB;
    const ushort* bp = BT + (size_t)(colbase + rlo) * KSTACK + (q << 3);
    f32x4 c0 = {0.f, 0.f, 0.f, 0.f};
    #pragma unroll 4
    for (int kk = 0; kk < KSTACK / 32; ++kk) {
        uint loff = (uint)(kk * 64 + q * 16) ^ x7;
        bf16x8 af = *(const bf16x8*)(arow + loff);
        bf16x8 b  = *(const bf16x8*)(bp + kk * 32);
        c0 = __builtin_amdgcn_mfma_f32_16x16x32_bf16(af, b, c0, 0, 0, 0);
    }
    int col = colbase + rlo;
    float bv = bias[col];
    int rowoff = q << 2;
    #pragma unroll
    for (int rg = 0; rg < 4; ++rg) {
        int row = blockrow + rowoff + rg;   // grid exact: row < NN always
        float v = c0[rg] + bv;
        if (hout) {
            v = fmaxf(v, 0.f);
            hout[(size_t)row * DD + col] = f2bf(v);
        } else {
            fout[(size_t)row * DD + col] = v;
        }
    }
}

extern "C" void kernel_launch(void* const* d_in, const int* in_sizes, int n_in,
                              void* d_out, int out_size, void* d_ws, size_t ws_size,
                              hipStream_t stream) {
    const float* x      = (const float*)d_in[0];
    const int*   ei     = (const int*)d_in[1];
    const int*   et     = (const int*)d_in[2];
    const float* basis0 = (const float*)d_in[3];
    const float* comp0  = (const float*)d_in[4];
    const float* root0  = (const float*)d_in[5];
    const float* bias0  = (const float*)d_in[6];
    const float* basis1 = (const float*)d_in[7];
    const float* comp1  = (const float*)d_in[8];
    const float* root1  = (const float*)d_in[9];
    const float* bias1  = (const float*)d_in[10];
    float* out = (float*)d_out;

    char* ws = (char*)d_ws;
    size_t off = 0;
    auto alloc = [&](size_t bytes) -> void* {
        void* p = ws + off;
        off += (bytes + 255) & ~(size_t)255;
        return p;
    };
    int*    deg_dr  = (int*)alloc((size_t)NR2 * 4);
    int*    cursor  = (int*)alloc((size_t)NR2 * 4);
    size_t zero_bytes = off;
    int*    row_ptr = (int*)alloc((size_t)(NN + 1) * 4);
    int*    bsum    = (int*)alloc(256 * 4);
    int2*   ekw     = (int2*)alloc((size_t)EE * 8);
    ushort* wT0     = (ushort*)alloc((size_t)DD * KSTACK * 2);
    ushort* wT1     = (ushort*)alloc((size_t)DD * KSTACK * 2);
    ushort* xb      = (ushort*)alloc((size_t)NN * DD * 2);
    ushort* h       = (ushort*)alloc((size_t)NN * DD * 2);
    if (off > ws_size) return;

    hipMemsetAsync(d_ws, 0, zero_bytes, stream);

    dim3 wgrid(KSTACK / 32, 2);   // 36 x 2
    k_build_w3<<<wgrid, 256, 0, stream>>>(basis0, comp0, root0, basis1, comp1, root1, wT0, wT1);
    k_cvt_bf16<<<6250, 256, 0, stream>>>(x, xb, NN * DD / 4);
    k_hist<<<3125, 256, 0, stream>>>(ei, et, deg_dr);
    k_scan1<<<196, 256, 0, stream>>>(deg_dr, bsum, NN);
    k_scan2<<<1, 256, 0, stream>>>(bsum, 196);
    k_scan3<<<196, 256, 0, stream>>>(deg_dr, bsum, row_ptr, NN);
    k_scatter<<<3125, 256, 0, stream>>>(ei, et, row_ptr, deg_dr, cursor, ekw);

    int fblocks = NN / RPB;   // 3125, exact
    k_fused9<<<fblocks, 512, 0, stream>>>(xb, row_ptr, ekw, wT0, bias0, h, nullptr);
    k_fused9<<<fblocks, 512, 0, stream>>>(h, row_ptr, ekw, wT1, bias1, nullptr, out);
}

// Round 12
// 375.381 us; speedup vs baseline: 1.0666x; 1.0666x over previous
//
#include <hip/hip_runtime.h>

#define NN 50000
#define EE 800000
#define DD 128
#define RR 8
#define SLOTS 9        // 8 rels + root/self
#define KSTACK 1152    // SLOTS*DD
#define NR2 (NN * RR)  // 400000
#define GRPB 32        // rows per gemmH block

typedef __attribute__((ext_vector_type(8))) short bf16x8;
typedef __attribute__((ext_vector_type(4))) float f32x4;

__device__ inline float bf2f(ushort u) {
    union { uint i; float f; } v; v.i = ((uint)u) << 16; return v.f;
}
__device__ inline ushort f2bf(float f) {
    uint b = __float_as_uint(f);
    uint r = (b + 0x7fffu + ((b >> 16) & 1u)) >> 16;
    return (ushort)r;
}

// Build BT[c][i] (c = s*128+o, i = 0..127) for both layers.
// Tiled LDS transpose: coalesced basis reads (o-major), coalesced 32B writes (i-major).
// Grid: (36 k-tiles, 2 layers). k = s*128+i global k-index = blockIdx.x*32 + kk.
__global__ void __launch_bounds__(256) k_build_w4(
        const float* __restrict__ b0, const float* __restrict__ c0,
        const float* __restrict__ r0, const float* __restrict__ b1,
        const float* __restrict__ c1, const float* __restrict__ r1,
        ushort* __restrict__ w0, ushort* __restrict__ w1) {
    __shared__ float tile[32][132];
    const float* basis = blockIdx.y ? b1 : b0;
    const float* comp  = blockIdx.y ? c1 : c0;
    const float* root  = blockIdx.y ? r1 : r0;
    ushort* wT         = blockIdx.y ? w1 : w0;
    int tid = threadIdx.x;
    int k0 = blockIdx.x * 32;
    #pragma unroll
    for (int it = 0; it < 16; ++it) {
        int idx = it * 256 + tid;
        int kk = idx >> 7, o = idx & 127;
        int k = k0 + kk;
        float val;
        if (k < RR * DD) {
            int r = k >> 7, i = k & 127;
            float s = 0.f;
            #pragma unroll
            for (int b = 0; b < 8; ++b) s += comp[r * 8 + b] * basis[(b * 128 + i) * 128 + o];
            val = s;
        } else {
            val = root[(k - RR * DD) * 128 + o];
        }
        tile[kk][o] = val;
    }
    __syncthreads();
    int o = tid >> 1, half = tid & 1;
    int s = k0 >> 7, i0 = k0 & 127;
    ushort* wp = wT + ((size_t)(s * 128 + o)) * 128 + i0 + half * 16;
    #pragma unroll
    for (int j = 0; j < 8; ++j) {
        float lo = tile[half * 16 + 2 * j][o];
        float hi = tile[half * 16 + 2 * j + 1][o];
        uint pk;
        asm("v_cvt_pk_bf16_f32 %0, %1, %2" : "=v"(pk) : "v"(lo), "v"(hi));
        *(uint*)(wp + 2 * j) = pk;
    }
}

__global__ void k_hist(const int* __restrict__ ei, const int* __restrict__ et,
                       int* __restrict__ deg_dr, int* __restrict__ row_cnt) {
    int e = blockIdx.x * 256 + threadIdx.x;
    if (e < EE) {
        int d = ei[EE + e], t = et[e];
        atomicAdd(&deg_dr[d * RR + t], 1);
        atomicAdd(&row_cnt[d], 1);
    }
}

__global__ void k_scan1(const int* __restrict__ cnt, int* __restrict__ bsum, int n) {
    __shared__ int s[256];
    int t = threadIdx.x;
    int i = blockIdx.x * 256 + t;
    s[t] = (i < n) ? cnt[i] : 0;
    __syncthreads();
    for (int o = 128; o > 0; o >>= 1) {
        if (t < o) s[t] += s[t + o];
        __syncthreads();
    }
    if (t == 0) bsum[blockIdx.x] = s[0];
}

__global__ void k_scan2(int* __restrict__ bsum, int nb) {
    __shared__ int s[256];
    int t = threadIdx.x;
    int v = (t < nb) ? bsum[t] : 0;
    s[t] = v;
    __syncthreads();
    for (int o = 1; o < 256; o <<= 1) {
        int u = (t >= o) ? s[t - o] : 0;
        __syncthreads();
        s[t] += u;
        __syncthreads();
    }
    if (t < nb) bsum[t] = s[t] - v;   // exclusive
}

__global__ void k_scan3(const int* __restrict__ cnt, const int* __restrict__ boff,
                        int* __restrict__ ptr, int n) {
    __shared__ int s[256];
    int t = threadIdx.x;
    int i = blockIdx.x * 256 + t;
    int v = (i < n) ? cnt[i] : 0;
    s[t] = v;
    __syncthreads();
    for (int o = 1; o < 256; o <<= 1) {
        int u = (t >= o) ? s[t - o] : 0;
        __syncthreads();
        s[t] += u;
        __syncthreads();
    }
    if (i < n) ptr[i + 1] = boff[blockIdx.x] + s[t];
    if (i == 0) ptr[0] = 0;
}

// Per edge at dst-sorted position: {key = src*9+rel, w = 1/deg(dst,rel)}.
__global__ void k_scatter(const int* __restrict__ ei, const int* __restrict__ et,
                          const int* __restrict__ row_ptr, const int* __restrict__ deg_dr,
                          int* __restrict__ cursor, int2* __restrict__ ekw) {
    int e = blockIdx.x * 256 + threadIdx.x;
    if (e < EE) {
        int s = ei[e], d = ei[EE + e], t = et[e];
        int p = row_ptr[d] + atomicAdd(&cursor[d], 1);
        int2 pk;
        pk.x = s * SLOTS + t;
        pk.y = __float_as_int(1.f / (float)deg_dr[d * RR + t]);
        ekw[p] = pk;
    }
}

// Dense transform: H[n][c] = sum_i A[n][i] * BT[c][i] for ALL 1152 c per block.
// Block = 512 threads (8 waves), 32 rows; wave -> 144 cols (9 frags) x 32 rows (2 frags).
// A staged once into 8KB XOR-swizzled LDS (f32 input converted inline for layer 0);
// B streamed from L2-resident BT (295KB); H written bf16.
__global__ void __launch_bounds__(512, 4) k_gemmH2(
        const float* __restrict__ Af32, const ushort* __restrict__ Abf,
        const ushort* __restrict__ BT, ushort* __restrict__ H) {
    __shared__ ushort at[GRPB * DD];   // 8192 B
    char* atb = (char*)at;
    int tid = threadIdx.x, wid = tid >> 6, lane = tid & 63;
    int blockrow = blockIdx.x * GRPB;

    // stage A-tile: thread t -> row t>>4, 16B bf16 segment (t&15)
    {
        int row = tid >> 4, seg = tid & 15;
        int gr = blockrow + row; if (gr > NN - 1) gr = NN - 1;
        uint4 pk;
        if (Af32) {
            const float4* sp = (const float4*)(Af32 + (size_t)gr * DD + seg * 8);
            float4 v0 = sp[0], v1 = sp[1];
            asm("v_cvt_pk_bf16_f32 %0, %1, %2" : "=v"(pk.x) : "v"(v0.x), "v"(v0.y));
            asm("v_cvt_pk_bf16_f32 %0, %1, %2" : "=v"(pk.y) : "v"(v0.z), "v"(v0.w));
            asm("v_cvt_pk_bf16_f32 %0, %1, %2" : "=v"(pk.z) : "v"(v1.x), "v"(v1.y));
            asm("v_cvt_pk_bf16_f32 %0, %1, %2" : "=v"(pk.w) : "v"(v1.z), "v"(v1.w));
        } else {
            pk = *(const uint4*)(Abf + (size_t)gr * DD + seg * 8);
        }
        uint off = (uint)(row * 256) + (((uint)seg * 16) ^ ((uint)(row & 7) << 4));
        *(uint4*)(atb + off) = pk;
    }
    __syncthreads();

    int rlo = lane & 15, q = lane >> 4;
    int colw = wid * 144;
    f32x4 acc[2][9];
    #pragma unroll
    for (int f = 0; f < 2; ++f)
        #pragma unroll
        for (int c = 0; c < 9; ++c) acc[f][c] = (f32x4){0.f, 0.f, 0.f, 0.f};

    const ushort* bp = BT + (size_t)(colw + rlo) * DD + q * 8;
    uint x7 = (uint)(rlo & 7) << 4;
    #pragma unroll
    for (int kk = 0; kk < 4; ++kk) {
        uint loff = ((uint)(kk * 64 + q * 16)) ^ x7;
        bf16x8 a0 = *(const bf16x8*)(atb + rlo * 256 + loff);
        bf16x8 a1 = *(const bf16x8*)(atb + (rlo + 16) * 256 + loff);
        #pragma unroll
        for (int c = 0; c < 9; ++c) {
            bf16x8 b = *(const bf16x8*)(bp + (size_t)c * 16 * DD + kk * 32);
            acc[0][c] = __builtin_amdgcn_mfma_f32_16x16x32_bf16(a0, b, acc[0][c], 0, 0, 0);
            acc[1][c] = __builtin_amdgcn_mfma_f32_16x16x32_bf16(a1, b, acc[1][c], 0, 0, 0);
        }
    }

    #pragma unroll
    for (int f = 0; f < 2; ++f) {
        #pragma unroll
        for (int c = 0; c < 9; ++c) {
            #pragma unroll
            for (int rg = 0; rg < 4; ++rg) {
                int row = blockrow + f * 16 + q * 4 + rg;
                if (row < NN)
                    H[(size_t)row * KSTACK + colw + c * 16 + rlo] = f2bf(acc[f][c][rg]);
            }
        }
    }
}

// Gather-aggregate: out[n] = bias + H[n*9+8] + sum_e w_e * H[key_e].
// One wave per dst row; flat edge loop, unroll 4. (Proven ~50us in R3.)
__global__ void __launch_bounds__(256) k_agg2(const ushort* __restrict__ H,
                                              const int* __restrict__ row_ptr,
                                              const int2* __restrict__ ekw,
                                              const float* __restrict__ bias,
                                              ushort* __restrict__ hout,
                                              float* __restrict__ fout) {
    int wid = threadIdx.x >> 6, lane = threadIdx.x & 63;
    int n = blockIdx.x * 4 + wid;   // grid exact: 12500*4 == NN
    int l2 = lane << 1;
    uint su = *(const uint*)(H + ((size_t)n * SLOTS + RR) * DD + l2);
    float a0 = bf2f((ushort)(su & 0xffffu));
    float a1 = bf2f((ushort)(su >> 16));
    int p = row_ptr[n], p1 = row_ptr[n + 1];
    for (; p + 4 <= p1; p += 4) {
        int2 e0 = ekw[p], e1 = ekw[p + 1], e2 = ekw[p + 2], e3 = ekw[p + 3];
        uint u0 = *(const uint*)(H + (size_t)e0.x * DD + l2);
        uint u1 = *(const uint*)(H + (size_t)e1.x * DD + l2);
        uint u2 = *(const uint*)(H + (size_t)e2.x * DD + l2);
        uint u3 = *(const uint*)(H + (size_t)e3.x * DD + l2);
        float w0 = __int_as_float(e0.y), w1 = __int_as_float(e1.y);
        float w2 = __int_as_float(e2.y), w3 = __int_as_float(e3.y);
        a0 += w0 * bf2f((ushort)(u0 & 0xffffu)) + w1 * bf2f((ushort)(u1 & 0xffffu))
            + w2 * bf2f((ushort)(u2 & 0xffffu)) + w3 * bf2f((ushort)(u3 & 0xffffu));
        a1 += w0 * bf2f((ushort)(u0 >> 16)) + w1 * bf2f((ushort)(u1 >> 16))
            + w2 * bf2f((ushort)(u2 >> 16)) + w3 * bf2f((ushort)(u3 >> 16));
    }
    for (; p < p1; ++p) {
        int2 e = ekw[p];
        uint u = *(const uint*)(H + (size_t)e.x * DD + l2);
        float w = __int_as_float(e.y);
        a0 += w * bf2f((ushort)(u & 0xffffu));
        a1 += w * bf2f((ushort)(u >> 16));
    }
    a0 += bias[l2];
    a1 += bias[l2 + 1];
    if (hout) {
        a0 = fmaxf(a0, 0.f);
        a1 = fmaxf(a1, 0.f);
        *(uint*)(hout + (size_t)n * DD + l2) = (uint)f2bf(a0) | ((uint)f2bf(a1) << 16);
    } else {
        float2 v; v.x = a0; v.y = a1;
        *(float2*)(fout + (size_t)n * DD + l2) = v;
    }
}

extern "C" void kernel_launch(void* const* d_in, const int* in_sizes, int n_in,
                              void* d_out, int out_size, void* d_ws, size_t ws_size,
                              hipStream_t stream) {
    const float* x      = (const float*)d_in[0];
    const int*   ei     = (const int*)d_in[1];
    const int*   et     = (const int*)d_in[2];
    const float* basis0 = (const float*)d_in[3];
    const float* comp0  = (const float*)d_in[4];
    const float* root0  = (const float*)d_in[5];
    const float* bias0  = (const float*)d_in[6];
    const float* basis1 = (const float*)d_in[7];
    const float* comp1  = (const float*)d_in[8];
    const float* root1  = (const float*)d_in[9];
    const float* bias1  = (const float*)d_in[10];
    float* out = (float*)d_out;

    char* ws = (char*)d_ws;
    size_t off = 0;
    auto alloc = [&](size_t bytes) -> void* {
        void* p = ws + off;
        off += (bytes + 255) & ~(size_t)255;
        return p;
    };
    int*    deg_dr  = (int*)alloc((size_t)NR2 * 4);
    int*    row_cnt = (int*)alloc((size_t)NN * 4);
    int*    cursor  = (int*)alloc((size_t)NN * 4);
    size_t zero_bytes = off;
    int*    row_ptr = (int*)alloc((size_t)(NN + 1) * 4);
    int*    bsum    = (int*)alloc(256 * 4);
    int2*   ekw     = (int2*)alloc((size_t)EE * 8);
    ushort* BT0     = (ushort*)alloc((size_t)KSTACK * DD * 2);
    ushort* BT1     = (ushort*)alloc((size_t)KSTACK * DD * 2);
    ushort* h       = (ushort*)alloc((size_t)NN * DD * 2);
    ushort* H       = (ushort*)alloc((size_t)NN * KSTACK * 2);
    if (off > ws_size) return;

    hipMemsetAsync(d_ws, 0, zero_bytes, stream);

    dim3 wgrid(KSTACK / 32, 2);   // 36 x 2
    k_build_w4<<<wgrid, 256, 0, stream>>>(basis0, comp0, root0, basis1, comp1, root1, BT0, BT1);
    k_hist<<<3125, 256, 0, stream>>>(ei, et, deg_dr, row_cnt);
    k_scan1<<<196, 256, 0, stream>>>(row_cnt, bsum, NN);
    k_scan2<<<1, 256, 0, stream>>>(bsum, 196);
    k_scan3<<<196, 256, 0, stream>>>(row_cnt, bsum, row_ptr, NN);
    k_scatter<<<3125, 256, 0, stream>>>(ei, et, row_ptr, deg_dr, cursor, ekw);

    int ggrid = (NN + GRPB - 1) / GRPB;   // 1563
    // Layer 0
    k_gemmH2<<<ggrid, 512, 0, stream>>>(x, nullptr, BT0, H);
    k_agg2<<<12500, 256, 0, stream>>>(H, row_ptr, ekw, bias0, h, nullptr);
    // Layer 1
    k_gemmH2<<<nullptr == nullptr ? ggrid : ggrid, 512, 0, stream>>>(nullptr, h, BT1, H);
    k_agg2<<<12500, 256, 0, stream>>>(H, row_ptr, ekw, bias1, nullptr, out);
}

// Round 13
// 363.864 us; speedup vs baseline: 1.1003x; 1.0317x over previous
//
#include <hip/hip_runtime.h>

#define NN 50000
#define EE 800000
#define DD 128
#define RR 8
#define SLOTS 9        // 8 rels + root/self
#define KSTACK 1152    // SLOTS*DD
#define NR2 (NN * RR)  // 400000
#define GRPB 32        // rows per gemmH block
#define STROW 304      // staging row stride bytes (152 bf16: 144 + 8 pad)
#define STW (GRPB * STROW)   // 9728 B per-wave staging

typedef __attribute__((ext_vector_type(8))) short bf16x8;
typedef __attribute__((ext_vector_type(4))) float f32x4;

__device__ inline float bf2f(ushort u) {
    union { uint i; float f; } v; v.i = ((uint)u) << 16; return v.f;
}
__device__ inline ushort f2bf(float f) {
    uint b = __float_as_uint(f);
    uint r = (b + 0x7fffu + ((b >> 16) & 1u)) >> 16;
    return (ushort)r;
}

// Build BT[c][i] (c = s*128+o, i = 0..127) for both layers.
// Tiled LDS transpose: coalesced basis reads (o-major), coalesced 32B writes (i-major).
__global__ void __launch_bounds__(256) k_build_w4(
        const float* __restrict__ b0, const float* __restrict__ c0,
        const float* __restrict__ r0, const float* __restrict__ b1,
        const float* __restrict__ c1, const float* __restrict__ r1,
        ushort* __restrict__ w0, ushort* __restrict__ w1) {
    __shared__ float tile[32][132];
    const float* basis = blockIdx.y ? b1 : b0;
    const float* comp  = blockIdx.y ? c1 : c0;
    const float* root  = blockIdx.y ? r1 : r0;
    ushort* wT         = blockIdx.y ? w1 : w0;
    int tid = threadIdx.x;
    int k0 = blockIdx.x * 32;
    #pragma unroll
    for (int it = 0; it < 16; ++it) {
        int idx = it * 256 + tid;
        int kk = idx >> 7, o = idx & 127;
        int k = k0 + kk;
        float val;
        if (k < RR * DD) {
            int r = k >> 7, i = k & 127;
            float s = 0.f;
            #pragma unroll
            for (int b = 0; b < 8; ++b) s += comp[r * 8 + b] * basis[(b * 128 + i) * 128 + o];
            val = s;
        } else {
            val = root[(k - RR * DD) * 128 + o];
        }
        tile[kk][o] = val;
    }
    __syncthreads();
    int o = tid >> 1, half = tid & 1;
    int s = k0 >> 7, i0 = k0 & 127;
    ushort* wp = wT + ((size_t)(s * 128 + o)) * 128 + i0 + half * 16;
    #pragma unroll
    for (int j = 0; j < 8; ++j) {
        float lo = tile[half * 16 + 2 * j][o];
        float hi = tile[half * 16 + 2 * j + 1][o];
        uint pk;
        asm("v_cvt_pk_bf16_f32 %0, %1, %2" : "=v"(pk) : "v"(lo), "v"(hi));
        *(uint*)(wp + 2 * j) = pk;
    }
}

__global__ void k_hist(const int* __restrict__ ei, const int* __restrict__ et,
                       int* __restrict__ deg_dr, int* __restrict__ row_cnt) {
    int e = blockIdx.x * 256 + threadIdx.x;
    if (e < EE) {
        int d = ei[EE + e], t = et[e];
        atomicAdd(&deg_dr[d * RR + t], 1);
        atomicAdd(&row_cnt[d], 1);
    }
}

__global__ void k_scan1(const int* __restrict__ cnt, int* __restrict__ bsum, int n) {
    __shared__ int s[256];
    int t = threadIdx.x;
    int i = blockIdx.x * 256 + t;
    s[t] = (i < n) ? cnt[i] : 0;
    __syncthreads();
    for (int o = 128; o > 0; o >>= 1) {
        if (t < o) s[t] += s[t + o];
        __syncthreads();
    }
    if (t == 0) bsum[blockIdx.x] = s[0];
}

__global__ void k_scan2(int* __restrict__ bsum, int nb) {
    __shared__ int s[256];
    int t = threadIdx.x;
    int v = (t < nb) ? bsum[t] : 0;
    s[t] = v;
    __syncthreads();
    for (int o = 1; o < 256; o <<= 1) {
        int u = (t >= o) ? s[t - o] : 0;
        __syncthreads();
        s[t] += u;
        __syncthreads();
    }
    if (t < nb) bsum[t] = s[t] - v;   // exclusive
}

__global__ void k_scan3(const int* __restrict__ cnt, const int* __restrict__ boff,
                        int* __restrict__ ptr, int n) {
    __shared__ int s[256];
    int t = threadIdx.x;
    int i = blockIdx.x * 256 + t;
    int v = (i < n) ? cnt[i] : 0;
    s[t] = v;
    __syncthreads();
    for (int o = 1; o < 256; o <<= 1) {
        int u = (t >= o) ? s[t - o] : 0;
        __syncthreads();
        s[t] += u;
        __syncthreads();
    }
    if (i < n) ptr[i + 1] = boff[blockIdx.x] + s[t];
    if (i == 0) ptr[0] = 0;
}

// Per edge at dst-sorted position: {key = src*9+rel, w = 1/deg(dst,rel)}.
__global__ void k_scatter(const int* __restrict__ ei, const int* __restrict__ et,
                          const int* __restrict__ row_ptr, const int* __restrict__ deg_dr,
                          int* __restrict__ cursor, int2* __restrict__ ekw) {
    int e = blockIdx.x * 256 + threadIdx.x;
    if (e < EE) {
        int s = ei[e], d = ei[EE + e], t = et[e];
        int p = row_ptr[d] + atomicAdd(&cursor[d], 1);
        int2 pk;
        pk.x = s * SLOTS + t;
        pk.y = __float_as_int(1.f / (float)deg_dr[d * RR + t]);
        ekw[p] = pk;
    }
}

// Dense transform: H[n][c] = sum_i A[n][i]*BT[c][i], all 1152 c per block.
// Block = 512 threads (8 waves), 32 rows; wave -> 144 cols (9 frags) x 32 rows.
// A staged in 8KB swizzled LDS; MFMA; then LDS-staged COALESCED epilogue:
// per-wave 32x144 tile -> padded LDS -> 9 x 16B global stores per lane
// (vs 72 x 2B scattered stores = the 91us store-issue wall in R12).
__global__ void __launch_bounds__(512, 2) k_gemmH3(
        const float* __restrict__ Af32, const ushort* __restrict__ Abf,
        const ushort* __restrict__ BT, ushort* __restrict__ H) {
    __shared__ char lds[8 * STW];   // 77,824 B; first 8KB doubles as A-tile
    char* atb = lds;
    int tid = threadIdx.x, wid = tid >> 6, lane = tid & 63;
    int blockrow = blockIdx.x * GRPB;

    // stage A-tile: thread t -> row t>>4, 16B bf16 segment (t&15)
    {
        int row = tid >> 4, seg = tid & 15;
        int gr = blockrow + row; if (gr > NN - 1) gr = NN - 1;
        uint4 pk;
        if (Af32) {
            const float4* sp = (const float4*)(Af32 + (size_t)gr * DD + seg * 8);
            float4 v0 = sp[0], v1 = sp[1];
            asm("v_cvt_pk_bf16_f32 %0, %1, %2" : "=v"(pk.x) : "v"(v0.x), "v"(v0.y));
            asm("v_cvt_pk_bf16_f32 %0, %1, %2" : "=v"(pk.y) : "v"(v0.z), "v"(v0.w));
            asm("v_cvt_pk_bf16_f32 %0, %1, %2" : "=v"(pk.z) : "v"(v1.x), "v"(v1.y));
            asm("v_cvt_pk_bf16_f32 %0, %1, %2" : "=v"(pk.w) : "v"(v1.z), "v"(v1.w));
        } else {
            pk = *(const uint4*)(Abf + (size_t)gr * DD + seg * 8);
        }
        uint off = (uint)(row * 256) + (((uint)seg * 16) ^ ((uint)(row & 7) << 4));
        *(uint4*)(atb + off) = pk;
    }
    __syncthreads();

    int rlo = lane & 15, q = lane >> 4;
    int colw = wid * 144;
    f32x4 acc[2][9];
    #pragma unroll
    for (int f = 0; f < 2; ++f)
        #pragma unroll
        for (int c = 0; c < 9; ++c) acc[f][c] = (f32x4){0.f, 0.f, 0.f, 0.f};

    const ushort* bp = BT + (size_t)(colw + rlo) * DD + q * 8;
    uint x7 = (uint)(rlo & 7) << 4;
    #pragma unroll
    for (int kk = 0; kk < 4; ++kk) {
        uint loff = ((uint)(kk * 64 + q * 16)) ^ x7;
        bf16x8 a0 = *(const bf16x8*)(atb + rlo * 256 + loff);
        bf16x8 a1 = *(const bf16x8*)(atb + (rlo + 16) * 256 + loff);
        #pragma unroll
        for (int c = 0; c < 9; ++c) {
            bf16x8 b = *(const bf16x8*)(bp + (size_t)c * 16 * DD + kk * 32);
            acc[0][c] = __builtin_amdgcn_mfma_f32_16x16x32_bf16(a0, b, acc[0][c], 0, 0, 0);
            acc[1][c] = __builtin_amdgcn_mfma_f32_16x16x32_bf16(a1, b, acc[1][c], 0, 0, 0);
        }
    }
    __syncthreads();   // retire all A-tile reads before LDS reuse

    // stage wave's 32x144 bf16 tile into padded LDS (row stride 304 B)
    char* stb = lds + wid * STW;
    #pragma unroll
    for (int f = 0; f < 2; ++f) {
        #pragma unroll
        for (int c = 0; c < 9; ++c) {
            #pragma unroll
            for (int rg = 0; rg < 4; ++rg) {
                int r = f * 16 + q * 4 + rg;
                *(ushort*)(stb + r * STROW + (c * 16 + rlo) * 2) = f2bf(acc[f][c][rg]);
            }
        }
    }
    // coalesced copy-out: 576 chunks of 16B per wave, 9 per lane; r = ci/18 via magic
    #pragma unroll
    for (int k = 0; k < 9; ++k) {
        int ci = k * 64 + lane;
        int r = (int)(((uint)ci * 58255u) >> 20);
        int j = ci - r * 18;
        int row = blockrow + r;
        if (row < NN) {
            uint4 v = *(const uint4*)(stb + r * STROW + j * 16);
            *(uint4*)(H + (size_t)row * KSTACK + colw + j * 8) = v;
        }
    }
}

// Gather-aggregate: out[n] = bias + H[n*9+8] + sum_e w_e * H[key_e].
// One wave per dst row; flat edge loop, unroll 4. (Proven ~50us.)
__global__ void __launch_bounds__(256) k_agg2(const ushort* __restrict__ H,
                                              const int* __restrict__ row_ptr,
                                              const int2* __restrict__ ekw,
                                              const float* __restrict__ bias,
                                              ushort* __restrict__ hout,
                                              float* __restrict__ fout) {
    int wid = threadIdx.x >> 6, lane = threadIdx.x & 63;
    int n = blockIdx.x * 4 + wid;   // grid exact: 12500*4 == NN
    int l2 = lane << 1;
    uint su = *(const uint*)(H + ((size_t)n * SLOTS + RR) * DD + l2);
    float a0 = bf2f((ushort)(su & 0xffffu));
    float a1 = bf2f((ushort)(su >> 16));
    int p = row_ptr[n], p1 = row_ptr[n + 1];
    for (; p + 4 <= p1; p += 4) {
        int2 e0 = ekw[p], e1 = ekw[p + 1], e2 = ekw[p + 2], e3 = ekw[p + 3];
        uint u0 = *(const uint*)(H + (size_t)e0.x * DD + l2);
        uint u1 = *(const uint*)(H + (size_t)e1.x * DD + l2);
        uint u2 = *(const uint*)(H + (size_t)e2.x * DD + l2);
        uint u3 = *(const uint*)(H + (size_t)e3.x * DD + l2);
        float w0 = __int_as_float(e0.y), w1 = __int_as_float(e1.y);
        float w2 = __int_as_float(e2.y), w3 = __int_as_float(e3.y);
        a0 += w0 * bf2f((ushort)(u0 & 0xffffu)) + w1 * bf2f((ushort)(u1 & 0xffffu))
            + w2 * bf2f((ushort)(u2 & 0xffffu)) + w3 * bf2f((ushort)(u3 & 0xffffu));
        a1 += w0 * bf2f((ushort)(u0 >> 16)) + w1 * bf2f((ushort)(u1 >> 16))
            + w2 * bf2f((ushort)(u2 >> 16)) + w3 * bf2f((ushort)(u3 >> 16));
    }
    for (; p < p1; ++p) {
        int2 e = ekw[p];
        uint u = *(const uint*)(H + (size_t)e.x * DD + l2);
        float w = __int_as_float(e.y);
        a0 += w * bf2f((ushort)(u & 0xffffu));
        a1 += w * bf2f((ushort)(u >> 16));
    }
    a0 += bias[l2];
    a1 += bias[l2 + 1];
    if (hout) {
        a0 = fmaxf(a0, 0.f);
        a1 = fmaxf(a1, 0.f);
        *(uint*)(hout + (size_t)n * DD + l2) = (uint)f2bf(a0) | ((uint)f2bf(a1) << 16);
    } else {
        float2 v; v.x = a0; v.y = a1;
        *(float2*)(fout + (size_t)n * DD + l2) = v;
    }
}

extern "C" void kernel_launch(void* const* d_in, const int* in_sizes, int n_in,
                              void* d_out, int out_size, void* d_ws, size_t ws_size,
                              hipStream_t stream) {
    const float* x      = (const float*)d_in[0];
    const int*   ei     = (const int*)d_in[1];
    const int*   et     = (const int*)d_in[2];
    const float* basis0 = (const float*)d_in[3];
    const float* comp0  = (const float*)d_in[4];
    const float* root0  = (const float*)d_in[5];
    const float* bias0  = (const float*)d_in[6];
    const float* basis1 = (const float*)d_in[7];
    const float* comp1  = (const float*)d_in[8];
    const float* root1  = (const float*)d_in[9];
    const float* bias1  = (const float*)d_in[10];
    float* out = (float*)d_out;

    char* ws = (char*)d_ws;
    size_t off = 0;
    auto alloc = [&](size_t bytes) -> void* {
        void* p = ws + off;
        off += (bytes + 255) & ~(size_t)255;
        return p;
    };
    int*    deg_dr  = (int*)alloc((size_t)NR2 * 4);
    int*    row_cnt = (int*)alloc((size_t)NN * 4);
    int*    cursor  = (int*)alloc((size_t)NN * 4);
    size_t zero_bytes = off;
    int*    row_ptr = (int*)alloc((size_t)(NN + 1) * 4);
    int*    bsum    = (int*)alloc(256 * 4);
    int2*   ekw     = (int2*)alloc((size_t)EE * 8);
    ushort* BT0     = (ushort*)alloc((size_t)KSTACK * DD * 2);
    ushort* BT1     = (ushort*)alloc((size_t)KSTACK * DD * 2);
    ushort* h       = (ushort*)alloc((size_t)NN * DD * 2);
    ushort* H       = (ushort*)alloc((size_t)NN * KSTACK * 2);
    if (off > ws_size) return;

    hipMemsetAsync(d_ws, 0, zero_bytes, stream);

    dim3 wgrid(KSTACK / 32, 2);   // 36 x 2
    k_build_w4<<<wgrid, 256, 0, stream>>>(basis0, comp0, root0, basis1, comp1, root1, BT0, BT1);
    k_hist<<<3125, 256, 0, stream>>>(ei, et, deg_dr, row_cnt);
    k_scan1<<<196, 256, 0, stream>>>(row_cnt, bsum, NN);
    k_scan2<<<1, 256, 0, stream>>>(bsum, 196);
    k_scan3<<<196, 256, 0, stream>>>(row_cnt, bsum, row_ptr, NN);
    k_scatter<<<3125, 256, 0, stream>>>(ei, et, row_ptr, deg_dr, cursor, ekw);

    int ggrid = (NN + GRPB - 1) / GRPB;   // 1563
    // Layer 0
    k_gemmH3<<<ggrid, 512, 0, stream>>>(x, nullptr, BT0, H);
    k_agg2<<<12500, 256, 0, stream>>>(H, row_ptr, ekw, bias0, h, nullptr);
    // Layer 1
    k_gemmH3<<<ggrid, 512, 0, stream>>>(nullptr, h, BT1, H);
    k_agg2<<<12500, 256, 0, stream>>>(H, row_ptr, ekw, bias1, nullptr, out);
}